// Round 2
// baseline (362.573 us; speedup 1.0000x reference)
//
#include <hip/hip_runtime.h>

// YOLO loss, MI355X. B=16, GH=GW=64, NA=3, NC=80, T=100, net=1024.
// y_pred/y_true: contiguous (196608, 85) fp32. true_boxes: (16,100,4) fp32.
// out: 16 fp32 per-batch loss.
//
// Structure: wave-autonomous pipeline. Each wave owns 32 rows (4 chunks x 8
// rows). Per chunk: coalesced float4 global->reg prefetch, ds_write to a
// private per-wave LDS region, 8 threads/row consume via LDS with shfl_xor
// width-8 merges. NO __syncthreads in the loop -> global prefetch of chunk
// c+1 stays in flight during compute of chunk c (only lgkmcnt(0) is waited).

#define NC 80
#define NT 100
#define ROW_F 85            // floats per row
#define CPB 12288           // rows per batch (64*64*3)
#define NTOT 196608         // total rows
#define ROWS_PER_BLOCK 128
#define ROWS_PER_WAVE 32
#define CHUNK_ROWS 8
#define NCHUNK 4            // ROWS_PER_WAVE / CHUNK_ROWS
#define CHUNK_F 680         // CHUNK_ROWS * ROW_F
#define CHUNK_F4 170        // CHUNK_F / 4

__device__ __forceinline__ float frcp(float x) { return __builtin_amdgcn_rcpf(x); }
__device__ __forceinline__ float fsig(float x) { return frcp(1.f + __expf(-x)); }

__global__ __launch_bounds__(256, 4) void yolo_loss_kernel(
    const float* __restrict__ y_pred,
    const float* __restrict__ y_true,
    const float* __restrict__ true_boxes,
    float* __restrict__ out)
{
    // per-wave staging: [wave][pred 680 | true 680] floats = 5440 B/wave
    __shared__ __align__(16) float slds[4][2 * CHUNK_F];
    __shared__ float4 sbox[NT];   // precomputed (minx,miny,maxx,maxy)
    __shared__ float  sarea[NT];

    const int tid  = threadIdx.x;
    const int widx = tid >> 6;
    const int lane = tid & 63;
    const int r    = lane >> 3;   // row within chunk (0..7)
    const int q    = lane & 7;    // worker within row (0..7)

    const int block_row0 = blockIdx.x * ROWS_PER_BLOCK;
    const int b = block_row0 / CPB;   // block-uniform: 128 | 12288

    if (tid < NT) {
        const float4 tb = *(const float4*)(true_boxes + (size_t)b * NT * 4 + tid * 4);
        float tx = tb.x * (1.f / 64.f),   ty = tb.y * (1.f / 64.f);
        float tw = tb.z * (1.f / 1024.f), th = tb.w * (1.f / 1024.f);
        sbox[tid]  = make_float4(tx - 0.5f * tw, ty - 0.5f * th,
                                 tx + 0.5f * tw, ty + 0.5f * th);
        sarea[tid] = tw * th;
    }
    __syncthreads();   // the only block barrier; everything below is wave-local

    const int wave_row0 = block_row0 + widx * ROWS_PER_WAVE;
    float* S = slds[widx];

    float4 a0, a1, b0, b1;
    float4 a2 = make_float4(0, 0, 0, 0), b2 = make_float4(0, 0, 0, 0);
    auto issue = [&](int c) {
        const size_t off = (size_t)(wave_row0 + c * CHUNK_ROWS) * ROW_F; // 16B-aligned span
        const float4* gp4 = (const float4*)(y_pred + off);
        const float4* gt4 = (const float4*)(y_true + off);
        a0 = gp4[lane]; a1 = gp4[lane + 64];
        b0 = gt4[lane]; b1 = gt4[lane + 64];
        if (lane < CHUNK_F4 - 128) { a2 = gp4[lane + 128]; b2 = gt4[lane + 128]; }
    };
    issue(0);

    float acc = 0.f;
    for (int c = 0; c < NCHUNK; ++c) {
        // stage regs -> LDS (compiler inserts the vmcnt wait on reg use)
        float4* SP = (float4*)S;              // pred region: 170 float4
        float4* ST = (float4*)(S + CHUNK_F);  // true region
        SP[lane] = a0; SP[lane + 64] = a1;
        ST[lane] = b0; ST[lane + 64] = b1;
        if (lane < CHUNK_F4 - 128) { SP[lane + 128] = a2; ST[lane + 128] = b2; }

        if (c + 1 < NCHUNK) issue(c + 1);   // prefetch stays in flight during compute

        // lgkmcnt(0) only: ds_writes visible wave-wide; vmcnt NOT drained.
        __builtin_amdgcn_s_waitcnt(0xC07F);
        __builtin_amdgcn_wave_barrier();

        const float* P = S + r * ROW_F;
        const float* T = P + CHUNK_F;
        const float p0 = P[0], p1 = P[1], p2 = P[2], p3 = P[3], p4 = P[4];
        const float t0 = T[0], t1 = T[1], t2 = T[2], t3 = T[3], om = T[4];

        const int grow = wave_row0 + c * CHUNK_ROWS + r;
        const int rem  = grow - b * CPB;
        const int gy   = rem / 192;
        const int rr   = rem - gy * 192;
        const int gx   = rr / 3;
        const int a    = rr - gx * 3;
        const float aw = (a == 0) ? 116.f : ((a == 1) ? 156.f : 373.f);
        const float ah = (a == 0) ? 90.f  : ((a == 1) ? 198.f : 326.f);

        // ---- classes: two-pass logsumexp + y_true argmax, split 10/thread ----
        const int cb = 5 + 10 * q;
        float mloc = -1e30f;
#pragma unroll
        for (int k = 0; k < 10; ++k) mloc = fmaxf(mloc, P[cb + k]);
        float tmax = -1e30f; int jm = 0;
#pragma unroll
        for (int k = 0; k < 10; ++k) {
            const float tv = T[cb + k];
            if (tv > tmax) { tmax = tv; jm = cb - 5 + k; }
        }
#pragma unroll
        for (int off = 1; off < 8; off <<= 1) {
            mloc = fmaxf(mloc, __shfl_xor(mloc, off, 64));
            const float otv = __shfl_xor(tmax, off, 64);
            const int   oj  = __shfl_xor(jm, off, 64);
            if (otv > tmax || (otv == tmax && oj < jm)) { tmax = otv; jm = oj; }
        }
        float sl = 0.f;
#pragma unroll
        for (int k = 0; k < 10; ++k) sl += __expf(P[cb + k] - mloc);
#pragma unroll
        for (int off = 1; off < 8; off <<= 1) sl += __shfl_xor(sl, off, 64);
        const float lse = mloc + __logf(sl);
        const float ce  = lse - P[5 + jm];   // -log_softmax at true class

        // ---- pred box + IoU vs 100 true boxes, split 13/thread ----
        const float predx = (float)gx + fsig(p0);
        const float predy = (float)gy + fsig(p1);
        const float conf  = fsig(p4);
        const float pw = __expf(p2) * aw * (1.f / 1024.f);
        const float ph = __expf(p3) * ah * (1.f / 1024.f);
        const float parea = pw * ph;
        const float px = predx * (1.f / 64.f), py = predy * (1.f / 64.f);
        const float pminx = px - 0.5f * pw, pmaxx = px + 0.5f * pw;
        const float pminy = py - 0.5f * ph, pmaxy = py + 0.5f * ph;

        float best = 0.f;
        for (int ti = q; ti < NT; ti += 8) {
            const float4 bx = sbox[ti];
            float iw = fminf(pmaxx, bx.z) - fmaxf(pminx, bx.x);
            float ih = fminf(pmaxy, bx.w) - fmaxf(pminy, bx.y);
            iw = fmaxf(iw, 0.f); ih = fmaxf(ih, 0.f);
            const float inter = iw * ih;
            best = fmaxf(best, inter * frcp(parea + sarea[ti] - inter));
        }
#pragma unroll
        for (int off = 1; off < 8; off <<= 1)
            best = fmaxf(best, __shfl_xor(best, off, 64));
        const float ignore = (best > 0.5f) ? 1.f : 0.f;

        // ---- deltas (computed redundantly on all 8 lanes; q==0 contributes) ----
        const float wsx = __expf(t2) * aw * (1.f / 1024.f);
        const float wsy = __expf(t3) * ah * (1.f / 1024.f);
        const float ws  = 2.f - wsx * wsy;
        const float omws = om * ws;
        const float dx = omws * (t0 - predx);
        const float dy = omws * (t1 - predy);
        const float dw = omws * (t2 - p2);
        const float dh = omws * (t3 - p3);
        float dc = -conf + om * (1.f - conf) * 5.f;
        dc *= (1.f - (1.f - om) * ignore);
        const float dcl = om * ce;

        const float val = dx * dx + dy * dy + dw * dw + dh * dh + dc * dc + dcl * dcl;
        acc += (q == 0) ? val : 0.f;
    }

    // wave reduce + one atomic per wave (rows of a wave share b: 32 | 12288)
#pragma unroll
    for (int off = 32; off > 0; off >>= 1) acc += __shfl_down(acc, off, 64);
    if (lane == 0) atomicAdd(out + b, acc);
}

extern "C" void kernel_launch(void* const* d_in, const int* in_sizes, int n_in,
                              void* d_out, int out_size, void* d_ws, size_t ws_size,
                              hipStream_t stream) {
    // inputs: [0]=input_image (shape-only, never read), [1]=y_pred, [2]=y_true, [3]=true_boxes
    const float* y_pred     = (const float*)d_in[1];
    const float* y_true     = (const float*)d_in[2];
    const float* true_boxes = (const float*)d_in[3];
    float* out = (float*)d_out;

    hipMemsetAsync(d_out, 0, (size_t)out_size * sizeof(float), stream);
    yolo_loss_kernel<<<NTOT / ROWS_PER_BLOCK, 256, 0, stream>>>(y_pred, y_true, true_boxes, out);
}